// Round 3
// baseline (231.369 us; speedup 1.0000x reference)
//
#include <hip/hip_runtime.h>
#include <math.h>

#define LN 8      // layers
#define NRBF 256
#define FD 16
#define OUTD 3

typedef __attribute__((ext_vector_type(8))) short short8;   // 8 x bf16
typedef __attribute__((ext_vector_type(4))) float floatx4;

__device__ __forceinline__ short f2bf(float f) {
    unsigned u = __builtin_bit_cast(unsigned, f);
    u += 0x7fffu + ((u >> 16) & 1u);          // RNE
    return (short)(u >> 16);
}

// Workspace:
//   PKB: short8[8][16][64]   B-fragments, lane-ordered. 128 KB
//        entry (j, nt, lane): n = nt*16+(lane&15), k = (lane>>4)*8+e,
//        m=k>>1, p=k&1 -> p? -2*A*C : A   (A=exp(beta[j,n,m]))
//   EPI: float4[8][16][16]   {KC*t3prefix, w0, w1, w2} at (j, nt, l), n=nt*16+l. 32 KB

#define KC (-0.72134752044f)   // -0.5 * log2(e)

__global__ __launch_bounds__(256) void prep_pkb(
    const float* __restrict__ centers, const float* __restrict__ betas,
    short* __restrict__ PKB)
{
    int t = blockIdx.x * 256 + threadIdx.x;   // 8192 threads
    int lane = t & 63;
    int nt   = (t >> 6) & 15;
    int j    = t >> 10;
    int n    = nt * 16 + (lane & 15);
    int kq   = lane >> 4;
    size_t base = ((size_t)(j * NRBF + n)) * FD + kq * 4;
    float4 bq = *(const float4*)(betas + base);
    float4 cq = *(const float4*)(centers + base);
    float a0 = __expf(bq.x), a1 = __expf(bq.y), a2 = __expf(bq.z), a3 = __expf(bq.w);
    short8 v;
    v[0] = f2bf(a0); v[1] = f2bf(-2.0f * a0 * cq.x);
    v[2] = f2bf(a1); v[3] = f2bf(-2.0f * a1 * cq.y);
    v[4] = f2bf(a2); v[5] = f2bf(-2.0f * a2 * cq.z);
    v[6] = f2bf(a3); v[7] = f2bf(-2.0f * a3 * cq.w);
    *((short8*)(PKB + (size_t)t * 8)) = v;
}

__global__ __launch_bounds__(1024) void prep_epi(
    const float* __restrict__ centers, const float* __restrict__ betas,
    const float* __restrict__ W, float* __restrict__ EPI)
{
    __shared__ float ls[LN * NRBF];           // per-layer sum_m A*C*C
    int t = threadIdx.x;
#pragma unroll
    for (int h = 0; h < 2; ++h) {
        int p = t + h * 1024;                 // p = j*256 + n
        const float* bp = betas   + (size_t)p * FD;
        const float* cp = centers + (size_t)p * FD;
        float s = 0.f;
#pragma unroll
        for (int q = 0; q < 4; ++q) {
            float4 bq = *(const float4*)(bp + q * 4);
            float4 cq = *(const float4*)(cp + q * 4);
            s = fmaf(__expf(bq.x) * cq.x, cq.x, s);
            s = fmaf(__expf(bq.y) * cq.y, cq.y, s);
            s = fmaf(__expf(bq.z) * cq.z, cq.z, s);
            s = fmaf(__expf(bq.w) * cq.w, cq.w, s);
        }
        ls[p] = s;
    }
    __syncthreads();
#pragma unroll
    for (int h = 0; h < 2; ++h) {
        int p = t + h * 1024;
        int j = p >> 8, n = p & 255;
        float t3 = 0.f;
        for (int jj = 0; jj <= j; ++jj) t3 += ls[jj * 256 + n];
        int nt = n >> 4, l = n & 15;
        float4 e;
        e.x = KC * t3;
        e.y = W[0 * (LN * NRBF) + j * NRBF + n];
        e.z = W[1 * (LN * NRBF) + j * NRBF + n];
        e.w = W[2 * (LN * NRBF) + j * NRBF + n];
        ((float4*)EPI)[(j * 16 + nt) * 16 + l] = e;
    }
}

// One wave = 16 samples; 16 nt-tiles x 8 layers of 16x16x32 bf16 MFMA.
// EPI staged in LDS once; PKB register double-buffered one nt ahead.
__global__ __launch_bounds__(256, 3) void rbf_mfma(
    const float* __restrict__ feats, const short* __restrict__ PKB,
    const float* __restrict__ EPI, const float* __restrict__ bias,
    float* __restrict__ out, int B)
{
    __shared__ float4 eps_s[LN * 16 * 16];    // 32 KB
    for (int i = threadIdx.x; i < LN * 16 * 16; i += 256)
        eps_s[i] = ((const float4*)EPI)[i];

    int lane = threadIdx.x & 63;
    int wid  = threadIdx.x >> 6;
    int ntile_total = (B + 15) >> 4;
    int tile = blockIdx.x * 4 + wid;
    bool tvalid = (tile < ntile_total);
    if (!tvalid) tile = ntile_total - 1;
    int b0 = tile * 16;
    int m  = lane & 15;
    int kq = lane >> 4;

    // A-fragments: lane holds sample b0+m, k-range kq*8.. of each layer
    int brow = b0 + m; if (brow >= B) brow = B - 1;
    const float* xrow = feats + (size_t)brow * (LN * FD) + kq * 4;
    short8 afrag[LN];
#pragma unroll
    for (int j = 0; j < LN; ++j) {
        float4 x = *((const float4*)(xrow + j * FD));
        short8 f;
        f[0] = f2bf(x.x * x.x); f[1] = f2bf(x.x);
        f[2] = f2bf(x.y * x.y); f[3] = f2bf(x.y);
        f[4] = f2bf(x.z * x.z); f[5] = f2bf(x.z);
        f[6] = f2bf(x.w * x.w); f[7] = f2bf(x.w);
        afrag[j] = f;
    }

    const short8* pb = (const short8*)PKB + lane;  // + (j*16+nt)*64

    short8 buf[2][LN];
#pragma unroll
    for (int j = 0; j < LN; ++j) buf[0][j] = pb[(j * 16 + 0) * 64];

    float oacc[12];
#pragma unroll
    for (int i = 0; i < 12; ++i) oacc[i] = 0.f;

    __syncthreads();

#pragma unroll 2
    for (int nt = 0; nt < 16; ++nt) {
        int cur = nt & 1, nx = cur ^ 1;
        if (nt < 15) {
#pragma unroll
            for (int j = 0; j < LN; ++j) buf[nx][j] = pb[(j * 16 + nt + 1) * 64];
        }
        floatx4 acc = {0.f, 0.f, 0.f, 0.f};
#pragma unroll
        for (int j = 0; j < LN; ++j) {
            acc = __builtin_amdgcn_mfma_f32_16x16x32_bf16(afrag[j], buf[cur][j], acc, 0, 0, 0);
            float4 e = eps_s[(j * 16 + nt) * 16 + m];
#pragma unroll
            for (int r = 0; r < 4; ++r) {
                float rv = __builtin_amdgcn_exp2f(fmaf(acc[r], KC, e.x));
                oacc[r * 3 + 0] = fmaf(rv, e.y, oacc[r * 3 + 0]);
                oacc[r * 3 + 1] = fmaf(rv, e.z, oacc[r * 3 + 1]);
                oacc[r * 3 + 2] = fmaf(rv, e.w, oacc[r * 3 + 2]);
            }
        }
    }

    // Reduce over the 16 n-lanes within each kq group
#pragma unroll
    for (int i = 0; i < 12; ++i) {
        oacc[i] += __shfl_xor(oacc[i], 1);
        oacc[i] += __shfl_xor(oacc[i], 2);
        oacc[i] += __shfl_xor(oacc[i], 4);
        oacc[i] += __shfl_xor(oacc[i], 8);
    }

    if (tvalid && m < OUTD) {
        float bv = bias[m];
#pragma unroll
        for (int r = 0; r < 4; ++r) {
            int row = b0 + kq * 4 + r;
            float v = (m == 0) ? oacc[r * 3 + 0] : (m == 1) ? oacc[r * 3 + 1] : oacc[r * 3 + 2];
            if (row < B) out[(size_t)row * OUTD + m] = v + bv;
        }
    }
}

extern "C" void kernel_launch(void* const* d_in, const int* in_sizes, int n_in,
                              void* d_out, int out_size, void* d_ws, size_t ws_size,
                              hipStream_t stream) {
    // inputs: 0=x (UNUSED by reference), 1=feats, 2=centers, 3=betas, 4=W, 5=b
    const float* feats   = (const float*)d_in[1];
    const float* centers = (const float*)d_in[2];
    const float* betas   = (const float*)d_in[3];
    const float* W       = (const float*)d_in[4];
    const float* bias    = (const float*)d_in[5];
    float* out = (float*)d_out;
    int B = in_sizes[1] / (LN * FD);

    short* PKB = (short*)d_ws;                       // 65536 shorts = 128 KB
    float* EPI = (float*)((char*)d_ws + 65536 * 2);  // 8192 floats = 32 KB

    prep_pkb<<<32, 256, 0, stream>>>(centers, betas, PKB);
    prep_epi<<<1, 1024, 0, stream>>>(centers, betas, W, EPI);

    int tiles  = (B + 15) / 16;
    int blocks = (tiles + 3) / 4;
    rbf_mfma<<<blocks, 256, 0, stream>>>(feats, PKB, EPI, bias, out, B);
}

// Round 4
// 167.499 us; speedup vs baseline: 1.3813x; 1.3813x over previous
//
#include <hip/hip_runtime.h>
#include <math.h>

#define LN 8      // layers
#define NRBF 256
#define FD 16
#define OUTD 3
#define KC (-0.72134752044f)   // -0.5 * log2(e)

typedef __attribute__((ext_vector_type(8))) short short8;   // 8 x bf16
typedef __attribute__((ext_vector_type(4))) float floatx4;

__device__ __forceinline__ short f2bf(float f) {
    unsigned u = __builtin_bit_cast(unsigned, f);
    u += 0x7fffu + ((u >> 16) & 1u);          // RNE
    return (short)(u >> 16);
}

// Workspace:
//   PKB: short8[(j*16+nt)*64 + lane]  (128 KB)  B-fragments, lane-ordered:
//        n = nt*16+(lane&15), k = (lane>>4)*8+e, m=k>>1 -> {A, -2*A*C}
//   EPI: float4[nt*128 + j*16 + l]   (32 KB)   {KC*t3prefix, w0, w1, w2}, n=nt*16+l

__global__ __launch_bounds__(256) void prep(
    const float* __restrict__ centers, const float* __restrict__ betas,
    const float* __restrict__ W, short* __restrict__ PKB, float* __restrict__ EPI)
{
    __shared__ float ls[LN * 32];
    int blk = blockIdx.x;
    int tid = threadIdx.x;
    if (blk < 32) {
        // ---- PKB: one thread per (j, nt, lane) ----
        int t = blk * 256 + tid;           // 8192 total
        int lane = t & 63;
        int nt   = (t >> 6) & 15;
        int j    = t >> 10;
        int n    = nt * 16 + (lane & 15);
        int kq   = lane >> 4;
        size_t base = ((size_t)(j * NRBF + n)) * FD + kq * 4;
        float4 bq = *(const float4*)(betas + base);
        float4 cq = *(const float4*)(centers + base);
        float a0 = __expf(bq.x), a1 = __expf(bq.y), a2 = __expf(bq.z), a3 = __expf(bq.w);
        short8 v;
        v[0] = f2bf(a0); v[1] = f2bf(-2.0f * a0 * cq.x);
        v[2] = f2bf(a1); v[3] = f2bf(-2.0f * a1 * cq.y);
        v[4] = f2bf(a2); v[5] = f2bf(-2.0f * a2 * cq.z);
        v[6] = f2bf(a3); v[7] = f2bf(-2.0f * a3 * cq.w);
        *((short8*)(PKB + (size_t)t * 8)) = v;
    } else {
        // ---- EPI: block handles a 32-wide n slice, all 8 layers ----
        int jj = tid >> 5;                  // 0..7
        int nl = tid & 31;
        int n  = (blk - 32) * 32 + nl;
        const float* bp = betas   + ((size_t)(jj * NRBF + n)) * FD;
        const float* cp = centers + ((size_t)(jj * NRBF + n)) * FD;
        float s = 0.f;
#pragma unroll
        for (int q = 0; q < 4; ++q) {
            float4 bq = *(const float4*)(bp + q * 4);
            float4 cq = *(const float4*)(cp + q * 4);
            s = fmaf(__expf(bq.x) * cq.x, cq.x, s);
            s = fmaf(__expf(bq.y) * cq.y, cq.y, s);
            s = fmaf(__expf(bq.z) * cq.z, cq.z, s);
            s = fmaf(__expf(bq.w) * cq.w, cq.w, s);
        }
        ls[jj * 32 + nl] = s;
        __syncthreads();
        float t3 = 0.f;
        for (int j2 = 0; j2 <= jj; ++j2) t3 += ls[j2 * 32 + nl];
        float4 e;
        e.x = KC * t3;
        e.y = W[0 * (LN * NRBF) + jj * NRBF + n];
        e.z = W[1 * (LN * NRBF) + jj * NRBF + n];
        e.w = W[2 * (LN * NRBF) + jj * NRBF + n];
        int nt = n >> 4, l = n & 15;
        ((float4*)EPI)[nt * 128 + jj * 16 + l] = e;
    }
}

// One wave = 16 samples; 16 nt-tiles x 8 layers of 16x16x32 bf16 MFMA with the
// running accumulator giving the prefix sum. PKB+EPI double-buffered in LDS via
// global_load_lds (width 16); single barrier per nt.
__global__ __launch_bounds__(256, 5) void rbf_mfma(
    const float* __restrict__ feats, const short* __restrict__ PKB,
    const float* __restrict__ EPI, const float* __restrict__ bias,
    float* __restrict__ out, int B)
{
    __shared__ short8 pk_s[2][LN * 64];    // 2 x 8 KB
    __shared__ float4 ep_s[2][128];        // 2 x 2 KB

    int tid  = threadIdx.x;
    int lane = tid & 63;
    int wid  = tid >> 6;
    int ntile_total = (B + 15) >> 4;
    int tile = blockIdx.x * 4 + wid;
    bool tvalid = (tile < ntile_total);
    if (!tvalid) tile = ntile_total - 1;
    int b0 = tile * 16;
    int m  = lane & 15;
    int kq = lane >> 4;

    // A-fragments: lane holds sample b0+m, k-range kq*8.. of each layer
    int brow = b0 + m; if (brow >= B) brow = B - 1;
    const float* xrow = feats + (size_t)brow * (LN * FD) + kq * 4;
    short8 afrag[LN];
#pragma unroll
    for (int j = 0; j < LN; ++j) {
        float4 x = *((const float4*)(xrow + j * FD));
        short8 f;
        f[0] = f2bf(x.x * x.x); f[1] = f2bf(x.x);
        f[2] = f2bf(x.y * x.y); f[3] = f2bf(x.y);
        f[4] = f2bf(x.z * x.z); f[5] = f2bf(x.z);
        f[6] = f2bf(x.w * x.w); f[7] = f2bf(x.w);
        afrag[j] = f;
    }

    int j0 = wid * 2, j1 = wid * 2 + 1;

#define STAGE(buf, nt)                                                                  \
    do {                                                                                \
        const short* g0 = PKB + (size_t)(((j0 * 16 + (nt)) * 64 + lane)) * 8;           \
        const short* g1 = PKB + (size_t)(((j1 * 16 + (nt)) * 64 + lane)) * 8;           \
        __builtin_amdgcn_global_load_lds(                                               \
            (const __attribute__((address_space(1))) void*)g0,                          \
            (__attribute__((address_space(3))) void*)&pk_s[buf][j0 * 64], 16, 0, 0);    \
        __builtin_amdgcn_global_load_lds(                                               \
            (const __attribute__((address_space(1))) void*)g1,                          \
            (__attribute__((address_space(3))) void*)&pk_s[buf][j1 * 64], 16, 0, 0);    \
        if (wid < 2) {                                                                  \
            const float* ge = EPI + (size_t)((nt) * 128 + wid * 64 + lane) * 4;         \
            __builtin_amdgcn_global_load_lds(                                           \
                (const __attribute__((address_space(1))) void*)ge,                      \
                (__attribute__((address_space(3))) void*)&ep_s[buf][wid * 64], 16, 0, 0);\
        }                                                                               \
    } while (0)

    STAGE(0, 0);

    float oacc[12];
#pragma unroll
    for (int i = 0; i < 12; ++i) oacc[i] = 0.f;

    __syncthreads();   // drains staging vmcnt; nt=0 data visible

#pragma unroll 1
    for (int nt = 0; nt < 16; ++nt) {
        int cur = nt & 1;
        if (nt < 15) STAGE(cur ^ 1, nt + 1);
        floatx4 acc = {0.f, 0.f, 0.f, 0.f};
#pragma unroll
        for (int j = 0; j < LN; ++j) {
            short8 bfrag = pk_s[cur][j * 64 + lane];
            acc = __builtin_amdgcn_mfma_f32_16x16x32_bf16(afrag[j], bfrag, acc, 0, 0, 0);
            float4 e = ep_s[cur][j * 16 + m];
#pragma unroll
            for (int r = 0; r < 4; ++r) {
                float rv = __builtin_amdgcn_exp2f(fmaf(acc[r], KC, e.x));
                oacc[r * 3 + 0] = fmaf(rv, e.y, oacc[r * 3 + 0]);
                oacc[r * 3 + 1] = fmaf(rv, e.z, oacc[r * 3 + 1]);
                oacc[r * 3 + 2] = fmaf(rv, e.w, oacc[r * 3 + 2]);
            }
        }
        __syncthreads();  // readers done with cur; stage(cur^1) complete
    }

    // Reduce over the 16 n-lanes within each kq group
#pragma unroll
    for (int i = 0; i < 12; ++i) {
        oacc[i] += __shfl_xor(oacc[i], 1);
        oacc[i] += __shfl_xor(oacc[i], 2);
        oacc[i] += __shfl_xor(oacc[i], 4);
        oacc[i] += __shfl_xor(oacc[i], 8);
    }

    if (tvalid && m < OUTD) {
        float bv = bias[m];
#pragma unroll
        for (int r = 0; r < 4; ++r) {
            int row = b0 + kq * 4 + r;
            float v = (m == 0) ? oacc[r * 3 + 0] : (m == 1) ? oacc[r * 3 + 1] : oacc[r * 3 + 2];
            if (row < B) out[(size_t)row * OUTD + m] = v + bv;
        }
    }
}

extern "C" void kernel_launch(void* const* d_in, const int* in_sizes, int n_in,
                              void* d_out, int out_size, void* d_ws, size_t ws_size,
                              hipStream_t stream) {
    // inputs: 0=x (UNUSED by reference), 1=feats, 2=centers, 3=betas, 4=W, 5=b
    const float* feats   = (const float*)d_in[1];
    const float* centers = (const float*)d_in[2];
    const float* betas   = (const float*)d_in[3];
    const float* W       = (const float*)d_in[4];
    const float* bias    = (const float*)d_in[5];
    float* out = (float*)d_out;
    int B = in_sizes[1] / (LN * FD);

    short* PKB = (short*)d_ws;                       // 65536 shorts = 128 KB
    float* EPI = (float*)((char*)d_ws + 65536 * 2);  // 8192 floats = 32 KB

    prep<<<40, 256, 0, stream>>>(centers, betas, W, PKB, EPI);

    int tiles  = (B + 15) / 16;
    int blocks = (tiles + 3) / 4;
    rbf_mfma<<<blocks, 256, 0, stream>>>(feats, PKB, EPI, bias, out, B);
}

// Round 5
// 165.113 us; speedup vs baseline: 1.4013x; 1.0145x over previous
//
#include <hip/hip_runtime.h>
#include <math.h>

#define LN 8      // layers
#define NRBF 256
#define FD 16
#define OUTD 3
#define KC (-0.72134752044f)   // -0.5 * log2(e)

typedef __attribute__((ext_vector_type(8))) short short8;   // 8 x bf16
typedef __attribute__((ext_vector_type(4))) float floatx4;
typedef __attribute__((ext_vector_type(2))) float floatx2;

__device__ __forceinline__ short f2bf(float f) {
    unsigned u = __builtin_bit_cast(unsigned, f);
    u += 0x7fffu + ((u >> 16) & 1u);          // RNE
    return (short)(u >> 16);
}

// Workspace:
//   PKB: short8[(j*16+nt)*64 + lane]  (128 KB)  B-fragments, lane-ordered:
//        n = nt*16+(lane&15), k = (lane>>4)*8+e, m=k>>1 -> {A, -2*A*C}
//   EPI: float4[nt*128 + j*16 + l]   (32 KB)   {KC*t3prefix, w0, w1, w2}, n=nt*16+l

__global__ __launch_bounds__(256) void prep(
    const float* __restrict__ centers, const float* __restrict__ betas,
    const float* __restrict__ W, short* __restrict__ PKB, float* __restrict__ EPI)
{
    __shared__ float ls[LN * 32];
    int blk = blockIdx.x;
    int tid = threadIdx.x;
    if (blk < 32) {
        // ---- PKB: one thread per (j, nt, lane) ----
        int t = blk * 256 + tid;           // 8192 total
        int lane = t & 63;
        int nt   = (t >> 6) & 15;
        int j    = t >> 10;
        int n    = nt * 16 + (lane & 15);
        int kq   = lane >> 4;
        size_t base = ((size_t)(j * NRBF + n)) * FD + kq * 4;
        float4 bq = *(const float4*)(betas + base);
        float4 cq = *(const float4*)(centers + base);
        float a0 = __expf(bq.x), a1 = __expf(bq.y), a2 = __expf(bq.z), a3 = __expf(bq.w);
        short8 v;
        v[0] = f2bf(a0); v[1] = f2bf(-2.0f * a0 * cq.x);
        v[2] = f2bf(a1); v[3] = f2bf(-2.0f * a1 * cq.y);
        v[4] = f2bf(a2); v[5] = f2bf(-2.0f * a2 * cq.z);
        v[6] = f2bf(a3); v[7] = f2bf(-2.0f * a3 * cq.w);
        *((short8*)(PKB + (size_t)t * 8)) = v;
    } else {
        // ---- EPI: block handles a 32-wide n slice, all 8 layers ----
        int jj = tid >> 5;                  // 0..7
        int nl = tid & 31;
        int n  = (blk - 32) * 32 + nl;
        const float* bp = betas   + ((size_t)(jj * NRBF + n)) * FD;
        const float* cp = centers + ((size_t)(jj * NRBF + n)) * FD;
        float s = 0.f;
#pragma unroll
        for (int q = 0; q < 4; ++q) {
            float4 bq = *(const float4*)(bp + q * 4);
            float4 cq = *(const float4*)(cp + q * 4);
            s = fmaf(__expf(bq.x) * cq.x, cq.x, s);
            s = fmaf(__expf(bq.y) * cq.y, cq.y, s);
            s = fmaf(__expf(bq.z) * cq.z, cq.z, s);
            s = fmaf(__expf(bq.w) * cq.w, cq.w, s);
        }
        ls[jj * 32 + nl] = s;
        __syncthreads();
        float t3 = 0.f;
        for (int j2 = 0; j2 <= jj; ++j2) t3 += ls[j2 * 32 + nl];
        float4 e;
        e.x = KC * t3;
        e.y = W[0 * (LN * NRBF) + jj * NRBF + n];
        e.z = W[1 * (LN * NRBF) + jj * NRBF + n];
        e.w = W[2 * (LN * NRBF) + jj * NRBF + n];
        int nt = n >> 4, l = n & 15;
        ((float4*)EPI)[nt * 128 + jj * 16 + l] = e;
    }
}

// One BLOCK = one 16-sample tile. 4 waves; wave w handles nt = w*4 .. w*4+3.
// No per-nt barriers; PKB/EPI read straight from L2 (hot, broadcast).
// Final cross-wave reduce through 768 B of LDS.
__global__ __launch_bounds__(256, 5) void rbf_mfma(
    const float* __restrict__ feats, const short* __restrict__ PKB,
    const float* __restrict__ EPI, const float* __restrict__ bias,
    float* __restrict__ out, int B)
{
    __shared__ float red[4][48];

    int tid  = threadIdx.x;
    int lane = tid & 63;
    int w    = tid >> 6;
    int b0   = blockIdx.x * 16;
    int m    = lane & 15;
    int kq   = lane >> 4;

    // A-fragments: lane holds sample b0+m, k-range kq*8.. of each layer
    int brow = b0 + m; if (brow >= B) brow = B - 1;
    const float* xrow = feats + (size_t)brow * (LN * FD) + kq * 4;
    short8 afrag[LN];
#pragma unroll
    for (int j = 0; j < LN; ++j) {
        float4 x = *((const float4*)(xrow + j * FD));
        short8 f;
        f[0] = f2bf(x.x * x.x); f[1] = f2bf(x.x);
        f[2] = f2bf(x.y * x.y); f[3] = f2bf(x.y);
        f[4] = f2bf(x.z * x.z); f[5] = f2bf(x.z);
        f[6] = f2bf(x.w * x.w); f[7] = f2bf(x.w);
        afrag[j] = f;
    }

    floatx2 o01[4];
    float   o2[4];
#pragma unroll
    for (int r = 0; r < 4; ++r) { o01[r] = (floatx2){0.f, 0.f}; o2[r] = 0.f; }

#pragma unroll 1
    for (int g = 0; g < 4; ++g) {
        int nt = w * 4 + g;
        const short8* pb = (const short8*)PKB + (size_t)nt * 64 + lane;  // + j*1024
        const float4* ep = (const float4*)EPI + (size_t)nt * 128 + m;    // + j*16
        floatx4 acc = {0.f, 0.f, 0.f, 0.f};
#pragma unroll
        for (int j = 0; j < LN; ++j) {
            short8 bfrag = pb[j * 16 * 64];
            float4 e     = ep[j * 16];
            acc = __builtin_amdgcn_mfma_f32_16x16x32_bf16(afrag[j], bfrag, acc, 0, 0, 0);
            floatx2 eyz = {e.y, e.z};
#pragma unroll
            for (int r = 0; r < 4; ++r) {
                float rv = __builtin_amdgcn_exp2f(fmaf(acc[r], KC, e.x));
                floatx2 rv2 = {rv, rv};
                o01[r] += rv2 * eyz;            // packed fp32 FMA candidate
                o2[r]   = fmaf(rv, e.w, o2[r]);
            }
        }
    }

    // intra-wave reduce over the 16 n-lanes (xor 1,2,4,8 stay within kq group)
    float oacc[12];
#pragma unroll
    for (int r = 0; r < 4; ++r) {
        oacc[r * 3 + 0] = o01[r].x;
        oacc[r * 3 + 1] = o01[r].y;
        oacc[r * 3 + 2] = o2[r];
    }
#pragma unroll
    for (int i = 0; i < 12; ++i) {
        oacc[i] += __shfl_xor(oacc[i], 1);
        oacc[i] += __shfl_xor(oacc[i], 2);
        oacc[i] += __shfl_xor(oacc[i], 4);
        oacc[i] += __shfl_xor(oacc[i], 8);
    }

    if (m < OUTD) {
#pragma unroll
        for (int r = 0; r < 4; ++r)
            red[w][kq * 12 + r * 3 + m] = oacc[r * 3 + m];
    }
    __syncthreads();

    if (tid < 48) {
        int o = tid % 3;
        int row = b0 + tid / 3;
        if (row < B) {
            float s = red[0][tid] + red[1][tid] + red[2][tid] + red[3][tid] + bias[o];
            out[(size_t)b0 * 3 + tid] = s;   // contiguous 192 B per block
        }
    }
}

extern "C" void kernel_launch(void* const* d_in, const int* in_sizes, int n_in,
                              void* d_out, int out_size, void* d_ws, size_t ws_size,
                              hipStream_t stream) {
    // inputs: 0=x (UNUSED by reference), 1=feats, 2=centers, 3=betas, 4=W, 5=b
    const float* feats   = (const float*)d_in[1];
    const float* centers = (const float*)d_in[2];
    const float* betas   = (const float*)d_in[3];
    const float* W       = (const float*)d_in[4];
    const float* bias    = (const float*)d_in[5];
    float* out = (float*)d_out;
    int B = in_sizes[1] / (LN * FD);

    short* PKB = (short*)d_ws;                       // 65536 shorts = 128 KB
    float* EPI = (float*)((char*)d_ws + 65536 * 2);  // 8192 floats = 32 KB

    prep<<<40, 256, 0, stream>>>(centers, betas, W, PKB, EPI);

    int tiles = (B + 15) / 16;
    rbf_mfma<<<tiles, 256, 0, stream>>>(feats, PKB, EPI, bias, out, B);
}

// Round 6
// 161.120 us; speedup vs baseline: 1.4360x; 1.0248x over previous
//
#include <hip/hip_runtime.h>
#include <math.h>

#define LN 8      // layers
#define NRBF 256
#define FD 16
#define OUTD 3
#define KC (-0.72134752044f)   // -0.5 * log2(e)

typedef __attribute__((ext_vector_type(8))) short short8;   // 8 x bf16
typedef __attribute__((ext_vector_type(4))) float floatx4;
typedef __attribute__((ext_vector_type(2))) float floatx2;

__device__ __forceinline__ short f2bf(float f) {
    unsigned u = __builtin_bit_cast(unsigned, f);
    u += 0x7fffu + ((u >> 16) & 1u);          // RNE
    return (short)(u >> 16);
}

// Workspace:
//   PKB: short8[(nt*8+j)*64 + lane]  (128 KB)  B-fragments, lane-ordered:
//        n = nt*16+(lane&15), k = (lane>>4)*8+e, m=k>>1 -> {A, -2*A*C}
//        j-stride = 1 KB -> immediate-offset friendly
//   EPI: float4[nt*128 + j*16 + l]   (32 KB)   {KC*t3prefix, w0, w1, w2}, n=nt*16+l

__global__ __launch_bounds__(256) void prep(
    const float* __restrict__ centers, const float* __restrict__ betas,
    const float* __restrict__ W, short* __restrict__ PKB, float* __restrict__ EPI)
{
    __shared__ float ls[LN * 32];
    int blk = blockIdx.x;
    int tid = threadIdx.x;
    if (blk < 32) {
        // ---- PKB: one thread per (j, nt, lane) ----
        int t = blk * 256 + tid;           // 8192 total
        int lane = t & 63;
        int nt   = (t >> 6) & 15;
        int j    = t >> 10;
        int n    = nt * 16 + (lane & 15);
        int kq   = lane >> 4;
        size_t base = ((size_t)(j * NRBF + n)) * FD + kq * 4;
        float4 bq = *(const float4*)(betas + base);
        float4 cq = *(const float4*)(centers + base);
        float a0 = __expf(bq.x), a1 = __expf(bq.y), a2 = __expf(bq.z), a3 = __expf(bq.w);
        short8 v;
        v[0] = f2bf(a0); v[1] = f2bf(-2.0f * a0 * cq.x);
        v[2] = f2bf(a1); v[3] = f2bf(-2.0f * a1 * cq.y);
        v[4] = f2bf(a2); v[5] = f2bf(-2.0f * a2 * cq.z);
        v[6] = f2bf(a3); v[7] = f2bf(-2.0f * a3 * cq.w);
        *((short8*)(PKB + (size_t)((nt * 8 + j) * 64 + lane) * 8)) = v;
    } else {
        // ---- EPI: block handles a 32-wide n slice, all 8 layers ----
        int jj = tid >> 5;                  // 0..7
        int nl = tid & 31;
        int n  = (blk - 32) * 32 + nl;
        const float* bp = betas   + ((size_t)(jj * NRBF + n)) * FD;
        const float* cp = centers + ((size_t)(jj * NRBF + n)) * FD;
        float s = 0.f;
#pragma unroll
        for (int q = 0; q < 4; ++q) {
            float4 bq = *(const float4*)(bp + q * 4);
            float4 cq = *(const float4*)(cp + q * 4);
            s = fmaf(__expf(bq.x) * cq.x, cq.x, s);
            s = fmaf(__expf(bq.y) * cq.y, cq.y, s);
            s = fmaf(__expf(bq.z) * cq.z, cq.z, s);
            s = fmaf(__expf(bq.w) * cq.w, cq.w, s);
        }
        ls[jj * 32 + nl] = s;
        __syncthreads();
        float t3 = 0.f;
        for (int j2 = 0; j2 <= jj; ++j2) t3 += ls[j2 * 32 + nl];
        float4 e;
        e.x = KC * t3;
        e.y = W[0 * (LN * NRBF) + jj * NRBF + n];
        e.z = W[1 * (LN * NRBF) + jj * NRBF + n];
        e.w = W[2 * (LN * NRBF) + jj * NRBF + n];
        int nt = n >> 4, l = n & 15;
        ((float4*)EPI)[nt * 128 + jj * 16 + l] = e;
    }
}

// One WAVE = one 16-sample tile, all 16 nt. Two independent nt-chains
// (nt, nt+8) interleaved per j-step for ILP; shared output accumulators.
__global__ __launch_bounds__(256, 4) void rbf_mfma(
    const float* __restrict__ feats, const short* __restrict__ PKB,
    const float* __restrict__ EPI, const float* __restrict__ bias,
    float* __restrict__ out, int B)
{
    int tid  = threadIdx.x;
    int lane = tid & 63;
    int wid  = tid >> 6;
    int ntile_total = (B + 15) >> 4;
    int tile = blockIdx.x * 4 + wid;
    bool tvalid = (tile < ntile_total);
    if (!tvalid) tile = ntile_total - 1;
    int b0 = tile * 16;
    int m  = lane & 15;
    int kq = lane >> 4;

    // A-fragments: lane holds sample b0+m, k-range kq*8.. of each layer
    int brow = b0 + m; if (brow >= B) brow = B - 1;
    const float* xrow = feats + (size_t)brow * (LN * FD) + kq * 4;
    short8 afrag[LN];
#pragma unroll
    for (int j = 0; j < LN; ++j) {
        float4 x = *((const float4*)(xrow + j * FD));
        short8 f;
        f[0] = f2bf(x.x * x.x); f[1] = f2bf(x.x);
        f[2] = f2bf(x.y * x.y); f[3] = f2bf(x.y);
        f[4] = f2bf(x.z * x.z); f[5] = f2bf(x.z);
        f[6] = f2bf(x.w * x.w); f[7] = f2bf(x.w);
        afrag[j] = f;
    }

    floatx2 o01[4];
    float   o2[4];
#pragma unroll
    for (int r = 0; r < 4; ++r) { o01[r] = (floatx2){0.f, 0.f}; o2[r] = 0.f; }

#pragma unroll 1
    for (int nt = 0; nt < 8; ++nt) {
        // chain 0: tile nt ; chain 1: tile nt+8
        const short8* pb0 = (const short8*)PKB + (size_t)(nt * 8) * 64 + lane;
        const short8* pb1 = pb0 + (size_t)8 * 8 * 64;
        const float4* ep0 = (const float4*)EPI + (size_t)nt * 128 + m;
        const float4* ep1 = ep0 + (size_t)8 * 128;
        floatx4 acc0 = {0.f, 0.f, 0.f, 0.f};
        floatx4 acc1 = {0.f, 0.f, 0.f, 0.f};
#pragma unroll
        for (int j = 0; j < LN; ++j) {
            short8 bf0 = pb0[j * 64];
            short8 bf1 = pb1[j * 64];
            float4 e0  = ep0[j * 16];
            float4 e1  = ep1[j * 16];
            acc0 = __builtin_amdgcn_mfma_f32_16x16x32_bf16(afrag[j], bf0, acc0, 0, 0, 0);
            acc1 = __builtin_amdgcn_mfma_f32_16x16x32_bf16(afrag[j], bf1, acc1, 0, 0, 0);
            floatx2 eyz0 = {e0.y, e0.z};
            floatx2 eyz1 = {e1.y, e1.z};
#pragma unroll
            for (int r = 0; r < 4; ++r) {
                float rv0 = __builtin_amdgcn_exp2f(fmaf(acc0[r], KC, e0.x));
                float rv1 = __builtin_amdgcn_exp2f(fmaf(acc1[r], KC, e1.x));
                floatx2 rv02 = {rv0, rv0};
                floatx2 rv12 = {rv1, rv1};
                o01[r] += rv02 * eyz0;
                o01[r] += rv12 * eyz1;
                o2[r]   = fmaf(rv0, e0.w, o2[r]);
                o2[r]   = fmaf(rv1, e1.w, o2[r]);
            }
        }
    }

    // intra-wave reduce over the 16 n-lanes (xor 1,2,4,8 stay within kq group)
    float oacc[12];
#pragma unroll
    for (int r = 0; r < 4; ++r) {
        oacc[r * 3 + 0] = o01[r].x;
        oacc[r * 3 + 1] = o01[r].y;
        oacc[r * 3 + 2] = o2[r];
    }
#pragma unroll
    for (int i = 0; i < 12; ++i) {
        oacc[i] += __shfl_xor(oacc[i], 1);
        oacc[i] += __shfl_xor(oacc[i], 2);
        oacc[i] += __shfl_xor(oacc[i], 4);
        oacc[i] += __shfl_xor(oacc[i], 8);
    }

    if (tvalid && m < OUTD) {
        float bv = bias[m];
#pragma unroll
        for (int r = 0; r < 4; ++r) {
            int row = b0 + kq * 4 + r;
            if (row < B) out[(size_t)row * OUTD + m] = oacc[r * 3 + m] + bv;
        }
    }
}

extern "C" void kernel_launch(void* const* d_in, const int* in_sizes, int n_in,
                              void* d_out, int out_size, void* d_ws, size_t ws_size,
                              hipStream_t stream) {
    // inputs: 0=x (UNUSED by reference), 1=feats, 2=centers, 3=betas, 4=W, 5=b
    const float* feats   = (const float*)d_in[1];
    const float* centers = (const float*)d_in[2];
    const float* betas   = (const float*)d_in[3];
    const float* W       = (const float*)d_in[4];
    const float* bias    = (const float*)d_in[5];
    float* out = (float*)d_out;
    int B = in_sizes[1] / (LN * FD);

    short* PKB = (short*)d_ws;                       // 65536 shorts = 128 KB
    float* EPI = (float*)((char*)d_ws + 65536 * 2);  // 8192 floats = 32 KB

    prep<<<40, 256, 0, stream>>>(centers, betas, W, PKB, EPI);

    int tiles  = (B + 15) / 16;
    int blocks = (tiles + 3) / 4;
    rbf_mfma<<<blocks, 256, 0, stream>>>(feats, PKB, EPI, bias, out, B);
}